// Round 7
// baseline (761.878 us; speedup 1.0000x reference)
//
#include <hip/hip_runtime.h>
#include <math.h>

typedef float f4 __attribute__((ext_vector_type(4)));

#define TOKENS 16384
#define DIM    4096
#define NE     64
#define KTOP   8
#define BKT    64               // K per W tile
#define NTILE  (DIM / BKT)      // 64 tiles
#define TPW    8                // tokens per wave
#define NWAVE  4
#define TPB    (TPW * NWAVE)    // 32 tokens/block
#define NT     256
#define NBLK   (TOKENS / TPB)   // 512 blocks -> 2 blocks/CU

#define GAS __attribute__((address_space(1)))
#define LAS __attribute__((address_space(3)))
#define GLD16(src, dst) \
    __builtin_amdgcn_global_load_lds((const GAS void*)(src), (LAS void*)(dst), 16, 0, 0)

// lane = expert. Only W goes through LDS (1 ds_read_b128 per 32 wave-FMAs);
// X rows are wave-uniform streams loaded directly (SMEM/VMEM pipe, 268 MB once).
// W tile layout (floats): slot(e,pc) = e*64 + pc*4 + j holds
//   W[e][kt*64 + (pc ^ (e&15) ^ ((e>>4)<<2))*4 + j]
// -> staging is dest-linear (global_load_lds-compatible, source pre-swizzled),
//    read of logical chunk c uses pc = c ^ xm, max 2-way banks (free).
__global__ __launch_bounds__(NT) void gate_topk_kernel(
    const float* __restrict__ x, const float* __restrict__ W,
    const float* __restrict__ bias, float* __restrict__ idx_out,
    float* __restrict__ val_out, float* __restrict__ blocksums)
{
    __shared__ __align__(16) float Ws[2][NE * BKT];   // 2 x 16 KB
    __shared__ float bsum[NWAVE];

    const int tid  = threadIdx.x;
    const int lane = tid & 63;
    const int wv   = tid >> 6;
    const int row0 = blockIdx.x * TPB;

    // ---- W staging sources (round s covers slots i2 = s*256+tid):
    //      e = s*16 + (tid>>4), pc = tid&15, swz = pc ^ (tid>>4) ^ (s<<2)
    const int pc = tid & 15;
    const int er = tid >> 4;
    const float* wsrc[4];
#pragma unroll
    for (int s = 0; s < 4; ++s)
        wsrc[s] = W + (size_t)(s * 16 + er) * DIM + ((pc ^ er ^ (s << 2)) << 2);

    // ---- W read side
    const int xm    = (lane & 15) ^ ((lane >> 4) << 2);
    const int wbase = lane * BKT;

    // ---- X row pointers: wave-uniform by construction (readfirstlane lets
    //      the compiler prove uniformity -> scalar loads / 1-line fetches)
    const float* xb[TPW];
#pragma unroll
    for (int t = 0; t < TPW; ++t) {
        const int token = __builtin_amdgcn_readfirstlane(row0 + wv * TPW + t);
        xb[t] = x + (size_t)token * DIM;
    }

    float acc[TPW] = {};

    // prologue: stage tile 0 into buf 0
#pragma unroll
    for (int s = 0; s < 4; ++s)
        GLD16(wsrc[s], &Ws[0][s * 1024 + wv * 256]);
    __syncthreads();

    for (int kt = 0; kt < NTILE; ++kt) {
        const int cur = kt & 1;
        if (kt + 1 < NTILE) {   // prefetch next W tile into the other buffer
#pragma unroll
            for (int s = 0; s < 4; ++s)
                GLD16(wsrc[s] + (size_t)(kt + 1) * BKT,
                      &Ws[cur ^ 1][s * 1024 + wv * 256]);
        }
        // two-level accumulation (fresh sub-acc per tile, top-k tie-safe)
        float sub[TPW] = {};
#pragma unroll
        for (int c = 0; c < 16; ++c) {
            const f4 w4 = *(const f4*)&Ws[cur][wbase + ((c ^ xm) << 2)];
#pragma unroll
            for (int t = 0; t < TPW; ++t) {
                const f4 xv = *(const f4*)(xb[t] + (c << 2));
                sub[t] = fmaf(xv[0], w4[0], sub[t]);
                sub[t] = fmaf(xv[1], w4[1], sub[t]);
                sub[t] = fmaf(xv[2], w4[2], sub[t]);
                sub[t] = fmaf(xv[3], w4[3], sub[t]);
            }
        }
#pragma unroll
        for (int t = 0; t < TPW; ++t) { acc[t] += sub[t]; xb[t] += BKT; }
        __syncthreads();   // next buffer staged; current safe to overwrite
    }

    // ---- epilogue: wave handles its 8 tokens; lane e holds logits[t][e]
    const float bv = bias[lane];
    float wsum = 0.0f;
#pragma unroll
    for (int tt = 0; tt < TPW; ++tt) {
        const float logit = acc[tt] + bv;
        float mx = logit;
#pragma unroll
        for (int off = 32; off > 0; off >>= 1)
            mx = fmaxf(mx, __shfl_xor(mx, off, 64));
        const float p = expf(logit - mx);
        float s = p;
#pragma unroll
        for (int off = 32; off > 0; off >>= 1)
            s += __shfl_xor(s, off, 64);           // identical tree on all lanes
        const float rs = 1.0f / s;
        const int token = row0 + wv * TPW + tt;
        float pv = p;
#pragma unroll
        for (int j = 0; j < KTOP; ++j) {
            float v = pv; int e = lane;
#pragma unroll
            for (int off = 1; off < 64; off <<= 1) {   // argmax, lower idx wins ties
                const float v2 = __shfl_xor(v, off, 64);
                const int   e2 = __shfl_xor(e, off, 64);
                if (v2 > v || (v2 == v && e2 < e)) { v = v2; e = e2; }
            }
            const float val = v * rs;
            if (lane == j) {
                idx_out[token * KTOP + j] = (float)e;   // d_out read back as flat f32
                val_out[token * KTOP + j] = val;        // raw; normalized by K2
            }
            if (lane == e) pv = -1.0f;
            wsum += val;                                // uniform across lanes
        }
    }
    if (lane == 0) bsum[wv] = wsum;
    __syncthreads();
    if (tid == 0)
        blocksums[blockIdx.x] = bsum[0] + bsum[1] + bsum[2] + bsum[3];
}

// K2: weights = vals / sum(all vals). Every thread computes the same serial sum
// of 512 partials (uniform -> scalarized, deterministic), then divides in place.
__global__ __launch_bounds__(256) void scale_kernel(
    const float* __restrict__ blocksums, float* __restrict__ vals)
{
    float total = 0.0f;
    for (int i = 0; i < NBLK; ++i) total += blocksums[i];
    const int i = blockIdx.x * blockDim.x + threadIdx.x;
    vals[i] = vals[i] / total;
}

extern "C" void kernel_launch(void* const* d_in, const int* in_sizes, int n_in,
                              void* d_out, int out_size, void* d_ws, size_t ws_size,
                              hipStream_t stream)
{
    const float* x = (const float*)d_in[0];
    const float* W = (const float*)d_in[1];
    const float* b = (const float*)d_in[2];
    float* idx_out = (float*)d_out;
    float* val_out = idx_out + (size_t)TOKENS * KTOP;
    float* blocksums = (float*)d_ws;

    gate_topk_kernel<<<NBLK, NT, 0, stream>>>(x, W, b, idx_out, val_out, blocksums);
    scale_kernel<<<(TOKENS * KTOP) / 256, 256, 0, stream>>>(blocksums, val_out);
}

// Round 8
// 214.784 us; speedup vs baseline: 3.5472x; 3.5472x over previous
//
#include <hip/hip_runtime.h>
#include <math.h>

typedef float f4 __attribute__((ext_vector_type(4)));

#define TOKENS 16384
#define DIM    4096
#define NE     64
#define KTOP   8
#define BM     64
#define BK     32
#define NGRP   4                  // single-wave K-split groups per block
#define KRANGE (DIM / NGRP)       // 1024 K per group
#define NTILE  (KRANGE / BK)      // 32 tiles per group
#define NT     256
#define NBLK   (TOKENS / BM)      // 256 blocks = 1 block/CU

// Gate GEMM + softmax + top-8. Block = 4 independent single-wave groups, each
// covering 1024 of K with an 8x8-per-thread register tile (1.0 B/MAC from LDS
// vs round-1's 2.0 — round 1 was LDS-pipe-bound at ~164us). Groups stage their
// own tiles (same-wave in-order LDS => NO barriers in the main loop).
// LDS layout per group (word offsets within the 4096-float region):
//   As[kk][m]: word kk*64 + ((m>>3)^(kk>>2))*8 + (m&7)   (XOR octet swizzle)
//   Bs likewise at +2048. Writes: 2-way banks; reads: 8-lane broadcast 32B
//   chunks, 2-way banks (free, m136). P[64][64] overlays As|Bs after a single
//   barrier for the 4-partial combine epilogue (round-4 proven).
__global__ __launch_bounds__(NT, 1) void gate_topk_kernel(
    const float* __restrict__ x, const float* __restrict__ W,
    const float* __restrict__ bias, float* __restrict__ idx_out,
    float* __restrict__ val_out, float* __restrict__ blocksums)
{
    __shared__ float smem[NGRP * 4096];   // 64 KB
    __shared__ float bsum[NGRP];

    const int tid = threadIdx.x;
    const int g   = tid >> 6;      // K-split group = wave
    const int t   = tid & 63;
    const int k4  = t & 7;         // staging f4-chunk (covers 32 k)
    const int m0  = t >> 3;        // staging row low-bits (rows m0+8s)
    const int tx  = t & 7;         // compute: expert octet
    const int ty  = t >> 3;        // compute: token octet
    const int row0 = blockIdx.x * BM;

    float* As = &smem[g * 4096];
    float* Bs = As + 2048;

    const float* xa = x + (size_t)(row0 + m0) * DIM + (g * KRANGE) + (k4 << 2);
    const float* wb = W + (size_t)m0 * DIM + (g * KRANGE) + (k4 << 2);

    float acc[8][8] = {};
    f4 fa[8], fb[8];

#define LOAD(kt) do {                                                   \
        _Pragma("unroll")                                               \
        for (int s = 0; s < 8; ++s) {                                   \
            fa[s] = *(const f4*)(xa + (size_t)(s << 3) * DIM + (kt) * BK); \
            fb[s] = *(const f4*)(wb + (size_t)(s << 3) * DIM + (kt) * BK); \
        }                                                               \
    } while (0)

#define WRITE_TILE() do {                                               \
        const int wbase = (k4 << 8) + m0;                               \
        _Pragma("unroll")                                               \
        for (int s = 0; s < 8; ++s) {                                   \
            const int so = ((s ^ k4) << 3);                             \
            _Pragma("unroll")                                           \
            for (int j = 0; j < 4; ++j) {                               \
                As[wbase + (j << 6) + so] = fa[s][j];                   \
                Bs[wbase + (j << 6) + so] = fb[s][j];                   \
            }                                                           \
        }                                                               \
    } while (0)

#define COMPUTE() do {                                                  \
        _Pragma("unroll")                                               \
        for (int k2 = 0; k2 < 8; ++k2) {                                \
            const int ao = ((ty ^ k2) << 3);                            \
            const int bo = ((tx ^ k2) << 3);                            \
            _Pragma("unroll")                                           \
            for (int j2 = 0; j2 < 4; ++j2) {                            \
                const int base = (((k2 << 2) + j2) << 6);               \
                const f4 A0 = *(const f4*)&As[base + ao];               \
                const f4 A1 = *(const f4*)&As[base + ao + 4];           \
                const f4 B0 = *(const f4*)&Bs[base + bo];               \
                const f4 B1 = *(const f4*)&Bs[base + bo + 4];           \
                _Pragma("unroll")                                       \
                for (int i = 0; i < 4; ++i) {                           \
                    _Pragma("unroll")                                   \
                    for (int j = 0; j < 4; ++j) {                       \
                        acc[i][j]         = fmaf(A0[i], B0[j], acc[i][j]);         \
                        acc[i][j + 4]     = fmaf(A0[i], B1[j], acc[i][j + 4]);     \
                        acc[i + 4][j]     = fmaf(A1[i], B0[j], acc[i + 4][j]);     \
                        acc[i + 4][j + 4] = fmaf(A1[i], B1[j], acc[i + 4][j + 4]); \
                    }                                                   \
                }                                                       \
            }                                                           \
        }                                                               \
    } while (0)

    LOAD(0);
    WRITE_TILE();
    for (int kt = 0; kt < NTILE - 1; ++kt) {
        LOAD(kt + 1);      // prefetch next tile into regs (~4096 cy ahead)
        COMPUTE();         // reads current tile (in-order before next writes)
        WRITE_TILE();      // same-wave program order protects the overwrite
    }
    COMPUTE();             // last tile

#undef LOAD
#undef WRITE_TILE
#undef COMPUTE

    // ---- partial logits P[g][m][e] overlay the group's As|Bs region.
    // Same-wave in-order LDS: our reads of the last tile complete first. The
    // barrier below makes all groups' P visible block-wide (round-3 lesson:
    // cross-thread reads of the GEMM buffers end before this point per group).
#pragma unroll
    for (int i = 0; i < 8; ++i) {
        const int pr = ((ty << 3) + i) << 6;
        f4 v0 = { acc[i][0], acc[i][1], acc[i][2], acc[i][3] };
        f4 v1 = { acc[i][4], acc[i][5], acc[i][6], acc[i][7] };
        *(f4*)&As[pr + (tx << 3)]     = v0;
        *(f4*)&As[pr + (tx << 3) + 4] = v1;
    }
    __syncthreads();   // the only barrier

    // ---- epilogue: wave g handles tokens 16g..16g+15; lane = expert
    const int lane = t;
    const float bv = bias[lane];
    float wsum = 0.0f;
#pragma unroll
    for (int tt = 0; tt < 16; ++tt) {
        const int tl = (g << 4) + tt;
        const int token = row0 + tl;
        const float logit = smem[0 * 4096 + tl * 64 + lane]
                          + smem[1 * 4096 + tl * 64 + lane]
                          + smem[2 * 4096 + tl * 64 + lane]
                          + smem[3 * 4096 + tl * 64 + lane] + bv;
        float mx = logit;
#pragma unroll
        for (int off = 32; off > 0; off >>= 1)
            mx = fmaxf(mx, __shfl_xor(mx, off, 64));
        const float p = expf(logit - mx);
        float s = p;
#pragma unroll
        for (int off = 32; off > 0; off >>= 1)
            s += __shfl_xor(s, off, 64);           // identical tree on all lanes
        const float rs = 1.0f / s;
        float pv = p;
#pragma unroll
        for (int j = 0; j < KTOP; ++j) {
            float v = pv; int e = lane;
#pragma unroll
            for (int off = 1; off < 64; off <<= 1) {   // argmax, lower idx wins ties
                const float v2 = __shfl_xor(v, off, 64);
                const int   e2 = __shfl_xor(e, off, 64);
                if (v2 > v || (v2 == v && e2 < e)) { v = v2; e = e2; }
            }
            const float val = v * rs;
            if (lane == j) {
                idx_out[token * KTOP + j] = (float)e;   // d_out read back as flat f32
                val_out[token * KTOP + j] = val;        // raw; normalized by K2
            }
            if (lane == e) pv = -1.0f;
            wsum += val;                                // uniform across lanes
        }
    }
    if (lane == 0) bsum[g] = wsum;
    __syncthreads();
    if (tid == 0)
        blocksums[blockIdx.x] = bsum[0] + bsum[1] + bsum[2] + bsum[3];
}

// K2: weights = vals / sum(all vals). Every thread computes the same serial sum
// of 256 partials (uniform -> scalarized, deterministic), then divides in place.
__global__ __launch_bounds__(256) void scale_kernel(
    const float* __restrict__ blocksums, float* __restrict__ vals)
{
    float total = 0.0f;
    for (int i = 0; i < NBLK; ++i) total += blocksums[i];
    const int i = blockIdx.x * blockDim.x + threadIdx.x;
    vals[i] = vals[i] / total;
}

extern "C" void kernel_launch(void* const* d_in, const int* in_sizes, int n_in,
                              void* d_out, int out_size, void* d_ws, size_t ws_size,
                              hipStream_t stream)
{
    const float* x = (const float*)d_in[0];
    const float* W = (const float*)d_in[1];
    const float* b = (const float*)d_in[2];
    float* idx_out = (float*)d_out;
    float* val_out = idx_out + (size_t)TOKENS * KTOP;
    float* blocksums = (float*)d_ws;

    gate_topk_kernel<<<NBLK, NT, 0, stream>>>(x, W, b, idx_out, val_out, blocksums);
    scale_kernel<<<(TOKENS * KTOP) / 256, 256, 0, stream>>>(blocksums, val_out);
}